// Round 3
// baseline (65.815 us; speedup 1.0000x reference)
//
#include <hip/hip_runtime.h>

// Problem constants: B=4, N=512, M=512, D=128, H=256, DOUT=128
#define BB    4
#define NN    512
#define MM    512
#define DD    128
#define HH    256
#define DOUTC 128
#define MSPLIT 4
#define MCHUNK (MM / MSPLIT)   // 128

typedef float v2f __attribute__((ext_vector_type(2)));

// ---------------------------------------------------------------------------
// Kernel 1: precompute   A[b,m,h] = Y[b,m]·W1[0:D,h] ; C[b,n,h] = X[b,n]·W1[D:2D,h]+b1[h]
// 512 blocks x 256 threads, 8 rows/block. Row data is wave-uniform -> compiler
// emits s_load; inner loop is v_fmac v,s,v (no LDS at all).
// ---------------------------------------------------------------------------
__global__ __launch_bounds__(256) void precompute_ac(
    const float* __restrict__ X, const float* __restrict__ Y,
    const float* __restrict__ W1, const float* __restrict__ b1,
    float* __restrict__ AC)
{
    const int bid = blockIdx.x;        // 0..511
    const int isC = bid >> 8;          // 0: A (from Y), 1: C (from X)
    const int r0  = (bid & 255) * 8;   // global row (b*512 + m)
    const int h   = threadIdx.x;

    const float* src = isC ? X : Y;
    const float* row = src + (size_t)r0 * DD;          // wave-uniform base
    const float* wp  = W1 + (isC ? DD * HH : 0) + h;   // per-thread column

    float acc[8] = {0.f, 0.f, 0.f, 0.f, 0.f, 0.f, 0.f, 0.f};

#pragma unroll 4
    for (int d = 0; d < DD; ++d) {
        const float w = wp[d * HH];                    // coalesced VMEM
#pragma unroll
        for (int r = 0; r < 8; ++r)
            acc[r] = fmaf(row[r * DD + d], w, acc[r]); // row[..] uniform -> s_load
    }

    const float bias = isC ? b1[h] : 0.f;
#pragma unroll
    for (int r = 0; r < 8; ++r)
        AC[((size_t)(isC * 2048 + r0 + r)) * HH + h] = acc[r] + bias;
}

// ---------------------------------------------------------------------------
// Kernel 2: abs-sum main loop (1.5 VALU instr/elem via relu(x)=(x+|x|)/2)
//   part[b,n,ms,h] = sum_{m in chunk} |A[b,m,h] + C[b,n,h]|
//   SAbuf[b,ms,h]  = sum_{m in chunk}  A[b,m,h]     (written by nt==0 blocks)
// grid = 4*64*4 = 1024 blocks x 256 threads. Thread = (h-pair, n-half).
// ---------------------------------------------------------------------------
__global__ __launch_bounds__(256) void abs_sum(
    const float* __restrict__ A, const float* __restrict__ C,
    float* __restrict__ part, float* __restrict__ SAbuf)
{
    const int bid = blockIdx.x;
    const int ms = bid & (MSPLIT - 1);
    const int nt = (bid >> 2) & 63;
    const int b  = bid >> 8;
    const int t  = threadIdx.x;
    const int h0 = (t & 127) * 2;
    const int nh = t >> 7;              // wave-uniform (waves 0,1 vs 2,3)
    const int n0 = nt * 8 + nh * 4;

    v2f c[4], acc[4];
#pragma unroll
    for (int i = 0; i < 4; ++i) {
        c[i] = *reinterpret_cast<const v2f*>(&C[((size_t)(b * NN + n0 + i)) * HH + h0]);
        acc[i] = (v2f){0.f, 0.f};
    }

    const float* Ab = A + ((size_t)(b * MM + ms * MCHUNK)) * HH + h0;
#pragma unroll 4
    for (int m = 0; m < MCHUNK; ++m) {
        const v2f a2 = *reinterpret_cast<const v2f*>(&Ab[(size_t)m * HH]);
#pragma unroll
        for (int i = 0; i < 4; ++i) {
            const v2f s = a2 + c[i];          // v_pk_add_f32
            acc[i].x += fabsf(s.x);           // v_add_f32 acc, |s|, acc
            acc[i].y += fabsf(s.y);
        }
    }

#pragma unroll
    for (int i = 0; i < 4; ++i)
        *reinterpret_cast<v2f*>(
            &part[(((size_t)(b * NN + n0 + i)) * MSPLIT + ms) * HH + h0]) = acc[i];

    // chunk-sum of A (needed once per (b,ms)): nt==0 blocks, lower 2 waves only
    if (nt == 0 && nh == 0) {
        v2f sa = (v2f){0.f, 0.f};
#pragma unroll 4
        for (int m = 0; m < MCHUNK; ++m)
            sa += *reinterpret_cast<const v2f*>(&Ab[(size_t)m * HH]);
        *reinterpret_cast<v2f*>(&SAbuf[((size_t)(b * MSPLIT + ms)) * HH + h0]) = sa;
    }
}

// ---------------------------------------------------------------------------
// Kernel 3: finalize
//   S[bn,h]  = 0.5*( SAt[b,h] + 512*C[bn,h] + sum_ms part[bn,ms,h] )
//   out[bn,o] = sum_h S[bn,h]*W2[h,o] + 512*b2[o]
// 512 blocks x 256 threads, 4 bn-rows/block (2 blocks/CU).
// ---------------------------------------------------------------------------
__global__ __launch_bounds__(256) void finalize(
    const float* __restrict__ part, const float* __restrict__ SAbuf,
    const float* __restrict__ C, const float* __restrict__ W2,
    const float* __restrict__ b2, float* __restrict__ out)
{
    __shared__ __align__(16) float S[4][HH];   // 4 KB
    const int bn0 = blockIdx.x * 4;
    const int b   = bn0 >> 9;
    const int t   = threadIdx.x;               // = h

    float sat = 0.f;
#pragma unroll
    for (int ms = 0; ms < MSPLIT; ++ms)
        sat += SAbuf[((size_t)(b * MSPLIT + ms)) * HH + t];

#pragma unroll
    for (int r = 0; r < 4; ++r) {
        float ab = 0.f;
#pragma unroll
        for (int ms = 0; ms < MSPLIT; ++ms)
            ab += part[((size_t)(bn0 + r) * MSPLIT + ms) * HH + t];
        S[r][t] = 0.5f * (sat + 512.f * C[(size_t)(bn0 + r) * HH + t] + ab);
    }
    __syncthreads();

    // GEMM: thread = (o-pair, row). o0 = 2*(t&63), r = t>>6 (wave-uniform).
    const int o0 = (t & 63) * 2;
    const int r  = t >> 6;

    const float bi = b2[o0] * 512.f;
    const float bj = b2[o0 + 1] * 512.f;
    v2f acc2 = (v2f){bi, bj};

    const float* w2p = W2 + o0;
#pragma unroll 4
    for (int k = 0; k < HH; ++k) {
        const v2f w2v = *reinterpret_cast<const v2f*>(&w2p[k * DOUTC]);  // coalesced
        const float sv = S[r][k];                                        // broadcast
        acc2.x = fmaf(sv, w2v.x, acc2.x);
        acc2.y = fmaf(sv, w2v.y, acc2.y);
    }

    *reinterpret_cast<v2f*>(&out[(size_t)(bn0 + r) * DOUTC + o0]) = acc2;
}

// ---------------------------------------------------------------------------
extern "C" void kernel_launch(void* const* d_in, const int* in_sizes, int n_in,
                              void* d_out, int out_size, void* d_ws, size_t ws_size,
                              hipStream_t stream) {
    const float* X  = (const float*)d_in[0];
    const float* Y  = (const float*)d_in[1];
    const float* W1 = (const float*)d_in[2];
    const float* b1 = (const float*)d_in[3];
    const float* W2 = (const float*)d_in[4];
    const float* b2 = (const float*)d_in[5];
    float* out = (float*)d_out;

    float* AC    = (float*)d_ws;                // 4 MB
    float* A     = AC;                          // rows 0..2047
    float* C     = AC + 2048 * HH;              // rows 2048..4095
    float* part  = AC + 4096 * HH;              // 8 MB
    float* SAbuf = part + (size_t)BB * NN * MSPLIT * HH;  // 16 KB

    hipLaunchKernelGGL(precompute_ac, dim3(512), dim3(256), 0, stream,
                       X, Y, W1, b1, AC);
    hipLaunchKernelGGL(abs_sum, dim3(BB * 64 * MSPLIT), dim3(256), 0, stream,
                       A, C, part, SAbuf);
    hipLaunchKernelGGL(finalize, dim3(BB * NN / 4), dim3(256), 0, stream,
                       part, SAbuf, C, W2, b2, out);
}